// Round 5
// baseline (157.169 us; speedup 1.0000x reference)
//
#include <hip/hip_runtime.h>
#include <math.h>

#define N_PROP 1000
#define N_CLS  81
#define N_FG   80
#define SCORE_THRESH 0.05f
#define NMS_THRESH   0.5f
#define DET_PER_IMG  100
#define BBOX_CLIP    4.135166556742356f   // ln(1000/16)

// d_out layout (560000 floats):
//   [0, 400000)        out5: (80*1000, 5)
//   [400000, 480000)   labels as float
//   [480000, 560000)   final mask as 0.0/1.0
#define LBL_OFF    400000
#define FIN_OFF    480000

// ws layout (bytes):
//   [0, 320)            int   svCnt[80]
//   [1024, 328704)      float svScore[80*1024]
//   [328704, 656384)    int   svRow[80*1024]
#define SV_STRIDE 1024

#define BLK 512

// ---------------- K_A: per-class self-contained NMS ------------------------
// block c: zero own output slice, compute class-c scores from logits,
// compact, rank-sort, decode valid boxes, bitmask-NMS, write kept rows
// optimistically, emit survivor slice.
__global__ __launch_bounds__(BLK)
void nms_all_kernel(const float* __restrict__ logits,
                    const float* __restrict__ reg,
                    const float* __restrict__ props,
                    const int* __restrict__ ihp,
                    const int* __restrict__ iwp,
                    float* __restrict__ out,
                    int* __restrict__ svCnt,
                    float* __restrict__ svScore,
                    int* __restrict__ svRow) {
    const int c = blockIdx.x;     // 0..79
    const int t = threadIdx.x;    // 0..511
    const int cls = c + 1;

    __shared__ float sSc[N_PROP];
    __shared__ int   sIdx[N_PROP];
    __shared__ int   sPos[N_PROP];
    __shared__ float sx1[N_PROP], sy1[N_PROP], sx2[N_PROP], sy2[N_PROP];
    __shared__ float sar[N_PROP], sSc2[N_PROP];
    __shared__ int   sJdx[N_PROP];
    __shared__ unsigned char sKeep[N_PROP];
    __shared__ unsigned long long smask[512][8];   // 32 KB IoU suppression bits
    __shared__ unsigned long long skeepW[8];
    __shared__ int   shV;
    __shared__ int   sSlot;

    // ---- phase 0: zero own output slice (fire-and-forget stores) ----
    {
        float4 z = make_float4(0.f, 0.f, 0.f, 0.f);
        float4* o5 = (float4*)(out + (size_t)c * N_PROP * 5);
        for (int i = t; i < 1250; i += BLK) o5[i] = z;
        float4* lb = (float4*)(out + LBL_OFF + (size_t)c * N_PROP);
        float4* fm = (float4*)(out + FIN_OFF + (size_t)c * N_PROP);
        for (int i = t; i < 250; i += BLK) { lb[i] = z; fm[i] = z; }
        if (t == 0) sSlot = 0;
    }

    // ---- phase 1: class-c scores for all proposals (two-pass softmax) ----
    for (int j = t; j < N_PROP; j += BLK) {
        const float* lr = logits + (size_t)j * N_CLS;
        float m = lr[0];
        for (int k = 1; k < N_CLS; ++k) m = fmaxf(m, lr[k]);
        float s = 0.0f;
        for (int k = 0; k < N_CLS; ++k) s += expf(lr[k] - m);
        sSc[j] = expf(lr[cls] - m) / s;
    }
    __syncthreads();

    // ---- phase 2: wave-0 ballot compaction (in place) ----
    if (t < 64) {
        const int lane = t;
        int V = 0;
        #pragma unroll
        for (int it = 0; it < 16; ++it) {
            int j = it * 64 + lane;
            float sc = (j < N_PROP) ? sSc[j] : -1.0f;
            bool val = (j < N_PROP) && (sc > SCORE_THRESH);
            unsigned long long mask = __ballot(val);
            int pre = __popcll(mask & ((1ULL << lane) - 1ULL));
            if (val) { sSc[V + pre] = sc; sIdx[V + pre] = j; }
            V += __popcll(mask);
        }
        if (lane == 0) shV = V;
    }
    __syncthreads();
    const int V = shV;

    // ---- phase 3: stable descending rank (ties -> lower original index) ----
    for (int v = t; v < V; v += BLK) {
        float s = sSc[v];
        int id = sIdx[v];
        int r = 0;
        for (int u = 0; u < V; ++u) {
            float su = sSc[u];
            r += (su > s) || (su == s && sIdx[u] < id);
        }
        sPos[v] = r;
    }
    __syncthreads();

    // ---- phase 4: gather into sorted slots + decode valid boxes ----
    const float W1 = (float)iwp[0] - 1.0f;
    const float H1 = (float)ihp[0] - 1.0f;
    for (int v = t; v < V; v += BLK) {
        int r = sPos[v];
        int j = sIdx[v];
        float4 pr = *(const float4*)(props + (size_t)j * 4);
        float w  = pr.z - pr.x + 1.0f;
        float h  = pr.w - pr.y + 1.0f;
        float cx = pr.x + 0.5f * w;
        float cy = pr.y + 0.5f * h;
        float4 rr = *(const float4*)(reg + ((size_t)j * N_CLS + cls) * 4);
        float dx = rr.x / 10.0f;
        float dy = rr.y / 10.0f;
        float dw = fminf(rr.z / 5.0f, BBOX_CLIP);
        float dh = fminf(rr.w / 5.0f, BBOX_CLIP);
        float pcx = dx * w + cx;
        float pcy = dy * h + cy;
        float pw = expf(dw) * w;
        float ph = expf(dh) * h;
        float bx1 = pcx - 0.5f * pw;
        float by1 = pcy - 0.5f * ph;
        float bx2 = pcx + 0.5f * pw - 1.0f;
        float by2 = pcy + 0.5f * ph - 1.0f;
        bx1 = fminf(fmaxf(bx1, 0.0f), W1);
        bx2 = fminf(fmaxf(bx2, 0.0f), W1);
        by1 = fminf(fmaxf(by1, 0.0f), H1);
        by2 = fminf(fmaxf(by2, 0.0f), H1);
        sx1[r] = bx1; sy1[r] = by1; sx2[r] = bx2; sy2[r] = by2;
        sar[r] = (bx2 - bx1 + 1.0f) * (by2 - by1 + 1.0f);
        sSc2[r] = sSc[v];
        sJdx[r] = j;
        sKeep[r] = 1;
    }
    __syncthreads();

    if (V <= 512) {
        // ---- phase 5a: parallel IoU bitmask build ----
        const int nW = (V + 63) >> 6;
        for (int r = t; r < V; r += BLK) {
            const float X1 = sx1[r], Y1 = sy1[r], X2 = sx2[r], Y2 = sy2[r], A = sar[r];
            for (int w = 0; w < nW; ++w) {
                unsigned long long bits = 0ull;
                int v0 = w << 6;
                int vs = (r + 1 > v0) ? r + 1 : v0;
                int ve = (V < v0 + 64) ? V : v0 + 64;
                for (int v = vs; v < ve; ++v) {
                    float iw = fminf(X2, sx2[v]) - fmaxf(X1, sx1[v]) + 1.0f;
                    float ih = fminf(Y2, sy2[v]) - fmaxf(Y1, sy1[v]) + 1.0f;
                    iw = fmaxf(iw, 0.0f);
                    ih = fmaxf(ih, 0.0f);
                    float inter = iw * ih;
                    float iou = inter / (A + sar[v] - inter);
                    if (iou > NMS_THRESH) bits |= 1ull << (v - v0);   // NaN-safe
                }
                smask[r][w] = bits;
            }
        }
        __syncthreads();

        // ---- phase 6a: single-thread greedy bit scan ----
        if (t == 0) {
            for (int w = 0; w < 8; ++w) {
                int rem = V - (w << 6);
                skeepW[w] = (rem >= 64) ? ~0ull : (rem <= 0 ? 0ull : ((1ull << rem) - 1ull));
            }
            for (int r = 0; r < V; ++r) {
                if ((skeepW[r >> 6] >> (r & 63)) & 1ull) {
                    for (int w = r >> 6; w < nW; ++w) skeepW[w] &= ~smask[r][w];
                }
            }
        }
        __syncthreads();
        for (int v = t; v < V; v += BLK)
            sKeep[v] = (unsigned char)((skeepW[v >> 6] >> (v & 63)) & 1ull);
        __syncthreads();
    } else {
        // ---- phase 5b/6b fallback: sequential suppression (proven loop) ----
        for (int r = 0; r < V; ++r) {
            if (sKeep[r]) {
                const float X1 = sx1[r], Y1 = sy1[r], X2 = sx2[r], Y2 = sy2[r], A = sar[r];
                for (int v = r + 1 + t; v < V; v += BLK) {
                    if (sKeep[v]) {
                        float iw = fminf(X2, sx2[v]) - fmaxf(X1, sx1[v]) + 1.0f;
                        float ih = fminf(Y2, sy2[v]) - fmaxf(Y1, sy1[v]) + 1.0f;
                        iw = fmaxf(iw, 0.0f);
                        ih = fmaxf(ih, 0.0f);
                        float inter = iw * ih;
                        float iou = inter / (A + sar[v] - inter);
                        if (iou > NMS_THRESH) sKeep[v] = 0;
                    }
                }
            }
            __syncthreads();
        }
    }

    // ---- phase 7: optimistic writes + survivor slice ----
    for (int v = t; v < V; v += BLK) {
        if (sKeep[v]) {
            int row = c * N_PROP + sJdx[v];
            size_t o = (size_t)row * 5;
            out[o + 0] = sx1[v];
            out[o + 1] = sy1[v];
            out[o + 2] = sx2[v];
            out[o + 3] = sy2[v];
            out[o + 4] = sSc2[v];
            out[LBL_OFF + row] = (float)cls;
            out[FIN_OFF + row] = 1.0f;
            int pos = atomicAdd(&sSlot, 1);
            svScore[c * SV_STRIDE + pos] = sSc2[v];
            svRow[c * SV_STRIDE + pos] = row;
        }
    }
    __syncthreads();
    if (t == 0) svCnt[c] = sSlot;
}

// ---------------- K_B: image threshold + fixup failing survivors -----------
__global__ __launch_bounds__(256)
void finalize_kernel(float* __restrict__ out,
                     const int* __restrict__ svCnt,
                     const float* __restrict__ svScore,
                     const int* __restrict__ svRow) {
    __shared__ int   cnt[N_FG];
    __shared__ int   off[N_FG + 1];
    __shared__ float lsc[8192];
    __shared__ int   red4[4];
    const int t = threadIdx.x;
    const int lane = t & 63;
    const int wave = t >> 6;

    if (t < N_FG) cnt[t] = svCnt[t];
    __syncthreads();
    if (t == 0) {
        int acc = 0;
        for (int c2 = 0; c2 < N_FG; ++c2) { off[c2] = acc; acc += cnt[c2]; }
        off[N_FG] = acc;
    }
    __syncthreads();
    const int n = off[N_FG];

    float th = 0.0f;   // kept scores all > 0.05 > 0 -> pass-all when n <= 100
    if (n > DET_PER_IMG) {
        const bool useL = (n <= 8192);
        if (useL) {
            for (int c2 = 0; c2 < N_FG; ++c2)
                for (int i = t; i < cnt[c2]; i += 256)
                    lsc[off[c2] + i] = svScore[c2 * SV_STRIDE + i];
            __syncthreads();
        }
        unsigned lo = 0u, hi = 0x40000000u;   // scores in (0.05, 1.0]
        while (hi - lo > 1u) {
            unsigned mid = lo + ((hi - lo) >> 1);
            float mv = __uint_as_float(mid);
            int cntGE = 0;
            if (useL) {
                for (int i = t; i < n; i += 256) cntGE += (lsc[i] >= mv) ? 1 : 0;
            } else {
                for (int c2 = 0; c2 < N_FG; ++c2)
                    for (int i = t; i < cnt[c2]; i += 256)
                        cntGE += (svScore[c2 * SV_STRIDE + i] >= mv) ? 1 : 0;
            }
            for (int offs = 32; offs; offs >>= 1) cntGE += __shfl_down(cntGE, offs);
            if (lane == 0) red4[wave] = cntGE;
            __syncthreads();
            int total = red4[0] + red4[1] + red4[2] + red4[3];
            __syncthreads();
            if (total >= DET_PER_IMG + 1) lo = mid; else hi = mid;
        }
        th = __uint_as_float(lo);
    }

    // fixup: zero out rows whose score fails the image threshold
    for (int c2 = 0; c2 < N_FG; ++c2) {
        for (int i = t; i < cnt[c2]; i += 256) {
            float sc = svScore[c2 * SV_STRIDE + i];
            if (sc < th) {
                int row = svRow[c2 * SV_STRIDE + i];
                size_t o = (size_t)row * 5;
                out[o + 0] = 0.0f;
                out[o + 1] = 0.0f;
                out[o + 2] = 0.0f;
                out[o + 3] = 0.0f;
                out[o + 4] = 0.0f;
                out[LBL_OFF + row] = 0.0f;
                out[FIN_OFF + row] = 0.0f;
            }
        }
    }
}

extern "C" void kernel_launch(void* const* d_in, const int* in_sizes, int n_in,
                              void* d_out, int out_size, void* d_ws, size_t ws_size,
                              hipStream_t stream) {
    const float* logits = (const float*)d_in[0];
    const float* reg    = (const float*)d_in[1];
    const float* props  = (const float*)d_in[2];
    const int*   ihp    = (const int*)d_in[3];
    const int*   iwp    = (const int*)d_in[4];
    float* out = (float*)d_out;

    char* ws = (char*)d_ws;
    int*   svCnt   = (int*)(ws + 0);
    float* svScore = (float*)(ws + 1024);
    int*   svRow   = (int*)(ws + 328704);

    nms_all_kernel<<<N_FG, BLK, 0, stream>>>(logits, reg, props, ihp, iwp,
                                             out, svCnt, svScore, svRow);
    finalize_kernel<<<1, 256, 0, stream>>>(out, svCnt, svScore, svRow);
}

// Round 6
// 74.515 us; speedup vs baseline: 2.1092x; 2.1092x over previous
//
#include <hip/hip_runtime.h>
#include <math.h>

#define N_PROP 1000
#define N_CLS  81
#define N_FG   80
#define SCORE_THRESH 0.05f
#define NMS_THRESH   0.5f
#define DET_PER_IMG  100
#define BBOX_CLIP    4.135166556742356f   // ln(1000/16)

// d_out layout (560000 floats):
//   [0, 400000)        out5: (80*1000, 5)
//   [400000, 480000)   labels as float
//   [480000, 560000)   final mask as 0.0/1.0
#define LBL_OFF    400000
#define FIN_OFF    480000

// ws layout (bytes):
//   [0,4)               int   survivor count
//   [4,8)               int   done counter (last-block flag)
//   [64, 320064)        float probT[80][1000]
//   [320064, 640064)    float compact survivor scores
//   [640064, 960064)    int   survivor row ids (c*1000+j)

// ---------------- K1: zero output + softmax -> probT (transposed) ----------
__global__ __launch_bounds__(256)
void softmax_zero_kernel(const float* __restrict__ logits,
                         float* __restrict__ out,
                         int* __restrict__ count,
                         int* __restrict__ done,
                         float* __restrict__ probT) {
    const int b = blockIdx.x;
    const int t = threadIdx.x;
    const int lane = t & 63;
    const int wave = t >> 6;
    if (b == 0 && t == 0) { *count = 0; *done = 0; }

    float4 z = make_float4(0.f, 0.f, 0.f, 0.f);
    float4* o4 = (float4*)out;
    for (int i = b * 256 + t; i < 140000; i += 250 * 256) o4[i] = z;

    const int n = b * 4 + wave;           // 250 blocks * 4 waves = 1000
    if (n < N_PROP) {
        const float* lrow = logits + (size_t)n * N_CLS;
        float v0 = lrow[lane];
        float v1 = (lane + 64 < N_CLS) ? lrow[lane + 64] : -INFINITY;
        float m = fmaxf(v0, v1);
        for (int off = 32; off; off >>= 1) m = fmaxf(m, __shfl_down(m, off));
        m = __shfl(m, 0);
        float e0 = expf(v0 - m);
        float e1 = (lane + 64 < N_CLS) ? expf(v1 - m) : 0.0f;
        float s = e0 + e1;
        for (int off = 32; off; off >>= 1) s += __shfl_down(s, off);
        s = __shfl(s, 0);
        if (lane >= 1)          probT[(size_t)(lane - 1) * N_PROP + n] = e0 / s;
        if (lane + 64 < N_CLS)  probT[(size_t)(lane + 63) * N_PROP + n] = e1 / s;
    }
}

// ---------------- K2: per-class NMS + last-block finalize -------------------
__global__ __launch_bounds__(256)
void nms_kernel(const float* __restrict__ probT,
                const float* __restrict__ props,
                const float* __restrict__ reg,
                const int* __restrict__ ihp,
                const int* __restrict__ iwp,
                float* __restrict__ out,
                int* __restrict__ count,
                int* __restrict__ done,
                float* __restrict__ compact,
                int* __restrict__ svRow) {
    const int c = blockIdx.x;     // 0..79
    const int t = threadIdx.x;    // 0..255
    const int lane = t & 63;
    const int wave = t >> 6;
    const int cls = c + 1;

    __shared__ float sSc[N_PROP];
    __shared__ int   sIdx[N_PROP];
    __shared__ int   sPos[N_PROP];
    __shared__ float sx1[N_PROP], sy1[N_PROP], sx2[N_PROP], sy2[N_PROP];
    __shared__ float sar[N_PROP], sSc2[N_PROP];
    __shared__ int   sJdx[N_PROP];
    __shared__ unsigned char sKeep[N_PROP];
    __shared__ unsigned long long smask[512][8];   // 32 KB; aliased as lsc in finalize
    __shared__ unsigned long long skeepW[8];
    __shared__ int   shV;
    __shared__ int   sLast;
    __shared__ int   red4[4];

    for (int j = t; j < N_PROP; j += 256) sSc[j] = probT[(size_t)c * N_PROP + j];
    __syncthreads();

    // wave-0 ballot compaction (in place; reads of a chunk precede its writes)
    if (wave == 0) {
        int V = 0;
        #pragma unroll
        for (int it = 0; it < 16; ++it) {
            int j = it * 64 + lane;
            float sc = (j < N_PROP) ? sSc[j] : -1.0f;
            bool val = (j < N_PROP) && (sc > SCORE_THRESH);
            unsigned long long mask = __ballot(val);
            int pre = __popcll(mask & ((1ULL << lane) - 1ULL));
            if (val) { sSc[V + pre] = sc; sIdx[V + pre] = j; }
            V += __popcll(mask);
        }
        if (lane == 0) shV = V;
    }
    __syncthreads();
    const int V = shV;

    // stable descending rank (ties -> lower original index)
    for (int v = t; v < V; v += 256) {
        float s = sSc[v];
        int id = sIdx[v];
        int r = 0;
        for (int u = 0; u < V; ++u) {
            float su = sSc[u];
            r += (su > s) || (su == s && sIdx[u] < id);
        }
        sPos[v] = r;
    }
    __syncthreads();

    // gather into sorted slots + decode boxes (valid entries only)
    const float W1 = (float)iwp[0] - 1.0f;
    const float H1 = (float)ihp[0] - 1.0f;
    for (int v = t; v < V; v += 256) {
        int r = sPos[v];
        int j = sIdx[v];
        float4 pr = *(const float4*)(props + (size_t)j * 4);
        float w  = pr.z - pr.x + 1.0f;
        float h  = pr.w - pr.y + 1.0f;
        float cx = pr.x + 0.5f * w;
        float cy = pr.y + 0.5f * h;
        float4 rr = *(const float4*)(reg + ((size_t)j * N_CLS + cls) * 4);
        float dx = rr.x / 10.0f;
        float dy = rr.y / 10.0f;
        float dw = fminf(rr.z / 5.0f, BBOX_CLIP);
        float dh = fminf(rr.w / 5.0f, BBOX_CLIP);
        float pcx = dx * w + cx;
        float pcy = dy * h + cy;
        float pw = expf(dw) * w;
        float ph = expf(dh) * h;
        float bx1 = pcx - 0.5f * pw;
        float by1 = pcy - 0.5f * ph;
        float bx2 = pcx + 0.5f * pw - 1.0f;
        float by2 = pcy + 0.5f * ph - 1.0f;
        bx1 = fminf(fmaxf(bx1, 0.0f), W1);
        bx2 = fminf(fmaxf(bx2, 0.0f), W1);
        by1 = fminf(fmaxf(by1, 0.0f), H1);
        by2 = fminf(fmaxf(by2, 0.0f), H1);
        sx1[r] = bx1; sy1[r] = by1; sx2[r] = bx2; sy2[r] = by2;
        sar[r] = (bx2 - bx1 + 1.0f) * (by2 - by1 + 1.0f);
        sSc2[r] = sSc[v];
        sJdx[r] = j;
        sKeep[r] = 1;
    }
    __syncthreads();

    if (V <= 512) {
        // parallel IoU bitmask build
        const int nW = (V + 63) >> 6;
        for (int r = t; r < V; r += 256) {
            const float X1 = sx1[r], Y1 = sy1[r], X2 = sx2[r], Y2 = sy2[r], A = sar[r];
            for (int w = 0; w < nW; ++w) {
                unsigned long long bits = 0ull;
                int v0 = w << 6;
                int vs = (r + 1 > v0) ? r + 1 : v0;
                int ve = (V < v0 + 64) ? V : v0 + 64;
                for (int v = vs; v < ve; ++v) {
                    float iw = fminf(X2, sx2[v]) - fmaxf(X1, sx1[v]) + 1.0f;
                    float ih = fminf(Y2, sy2[v]) - fmaxf(Y1, sy1[v]) + 1.0f;
                    iw = fmaxf(iw, 0.0f);
                    ih = fmaxf(ih, 0.0f);
                    float inter = iw * ih;
                    float iou = inter / (A + sar[v] - inter);
                    if (iou > NMS_THRESH) bits |= 1ull << (v - v0);   // NaN-safe
                }
                smask[r][w] = bits;
            }
        }
        __syncthreads();

        // single-thread greedy bit scan (== sorted sequential NMS)
        if (t == 0) {
            for (int w = 0; w < 8; ++w) {
                int rem = V - (w << 6);
                skeepW[w] = (rem >= 64) ? ~0ull : (rem <= 0 ? 0ull : ((1ull << rem) - 1ull));
            }
            for (int r = 0; r < V; ++r) {
                if ((skeepW[r >> 6] >> (r & 63)) & 1ull) {
                    for (int w = r >> 6; w < (int)((V + 63) >> 6); ++w) skeepW[w] &= ~smask[r][w];
                }
            }
        }
        __syncthreads();
        for (int v = t; v < V; v += 256)
            sKeep[v] = (unsigned char)((skeepW[v >> 6] >> (v & 63)) & 1ull);
        __syncthreads();
    } else {
        // fallback: proven sequential suppression
        for (int r = 0; r < V; ++r) {
            if (sKeep[r]) {
                const float X1 = sx1[r], Y1 = sy1[r], X2 = sx2[r], Y2 = sy2[r], A = sar[r];
                for (int v = r + 1 + t; v < V; v += 256) {
                    if (sKeep[v]) {
                        float iw = fminf(X2, sx2[v]) - fmaxf(X1, sx1[v]) + 1.0f;
                        float ih = fminf(Y2, sy2[v]) - fmaxf(Y1, sy1[v]) + 1.0f;
                        iw = fmaxf(iw, 0.0f);
                        ih = fmaxf(ih, 0.0f);
                        float inter = iw * ih;
                        float iou = inter / (A + sar[v] - inter);
                        if (iou > NMS_THRESH) sKeep[v] = 0;
                    }
                }
            }
            __syncthreads();
        }
    }

    // optimistic writes + flat survivor append
    for (int v = t; v < V; v += 256) {
        if (sKeep[v]) {
            int row = c * N_PROP + sJdx[v];
            size_t o = (size_t)row * 5;
            out[o + 0] = sx1[v];
            out[o + 1] = sy1[v];
            out[o + 2] = sx2[v];
            out[o + 3] = sy2[v];
            out[o + 4] = sSc2[v];
            out[LBL_OFF + row] = (float)cls;
            out[FIN_OFF + row] = 1.0f;
            int pos = atomicAdd(count, 1);
            compact[pos] = sSc2[v];
            svRow[pos] = row;
        }
    }
    __syncthreads();

    // ---- last-block finalize ----
    __threadfence();
    if (t == 0) {
        int old = __hip_atomic_fetch_add(done, 1, __ATOMIC_ACQ_REL, __HIP_MEMORY_SCOPE_AGENT);
        sLast = (old == N_FG - 1) ? 1 : 0;
    }
    __syncthreads();
    if (!sLast) return;
    __threadfence();

    const int n = __hip_atomic_load(count, __ATOMIC_RELAXED, __HIP_MEMORY_SCOPE_AGENT);
    float* lsc = (float*)smask;   // 8192 floats

    float th = 0.0f;   // survivors all > 0.05 > 0 -> pass-all when n <= 100
    const bool useL = (n <= 8192);
    if (n > DET_PER_IMG) {
        if (useL) {
            for (int i = t; i < n; i += 256)
                lsc[i] = __hip_atomic_load(&compact[i], __ATOMIC_RELAXED, __HIP_MEMORY_SCOPE_AGENT);
            __syncthreads();
        }
        unsigned lo = 0x3D4CCCCCu, hi = 0x40000000u;  // scores in (0.05, 1.0]
        while (hi - lo > 1u) {
            unsigned mid = lo + ((hi - lo) >> 1);
            float mv = __uint_as_float(mid);
            int cnt = 0;
            if (useL) {
                for (int i = t; i < n; i += 256) cnt += (lsc[i] >= mv) ? 1 : 0;
            } else {
                for (int i = t; i < n; i += 256)
                    cnt += (__hip_atomic_load(&compact[i], __ATOMIC_RELAXED, __HIP_MEMORY_SCOPE_AGENT) >= mv) ? 1 : 0;
            }
            for (int off = 32; off; off >>= 1) cnt += __shfl_down(cnt, off);
            if (lane == 0) red4[wave] = cnt;
            __syncthreads();
            int total = red4[0] + red4[1] + red4[2] + red4[3];
            __syncthreads();
            if (total >= DET_PER_IMG + 1) lo = mid; else hi = mid;
        }
        th = __uint_as_float(lo);
    }

    // fixup: zero rows whose score fails the image threshold
    for (int i = t; i < n; i += 256) {
        float sc = useL ? lsc[i]
                        : __hip_atomic_load(&compact[i], __ATOMIC_RELAXED, __HIP_MEMORY_SCOPE_AGENT);
        if (sc < th) {
            int row = __hip_atomic_load(&svRow[i], __ATOMIC_RELAXED, __HIP_MEMORY_SCOPE_AGENT);
            size_t o = (size_t)row * 5;
            out[o + 0] = 0.0f;
            out[o + 1] = 0.0f;
            out[o + 2] = 0.0f;
            out[o + 3] = 0.0f;
            out[o + 4] = 0.0f;
            out[LBL_OFF + row] = 0.0f;
            out[FIN_OFF + row] = 0.0f;
        }
    }
}

extern "C" void kernel_launch(void* const* d_in, const int* in_sizes, int n_in,
                              void* d_out, int out_size, void* d_ws, size_t ws_size,
                              hipStream_t stream) {
    const float* logits = (const float*)d_in[0];
    const float* reg    = (const float*)d_in[1];
    const float* props  = (const float*)d_in[2];
    const int*   ihp    = (const int*)d_in[3];
    const int*   iwp    = (const int*)d_in[4];
    float* out = (float*)d_out;

    char* ws = (char*)d_ws;
    int*   count   = (int*)(ws + 0);
    int*   done    = (int*)(ws + 4);
    float* probT   = (float*)(ws + 64);
    float* compact = (float*)(ws + 320064);
    int*   svRow   = (int*)(ws + 640064);

    softmax_zero_kernel<<<250, 256, 0, stream>>>(logits, out, count, done, probT);
    nms_kernel<<<N_FG, 256, 0, stream>>>(probT, props, reg, ihp, iwp,
                                         out, count, done, compact, svRow);
}